// Round 7
// baseline (326.831 us; speedup 1.0000x reference)
//
#include <hip/hip_runtime.h>
#include <hip/hip_fp16.h>

#define WG 256

typedef _Float16 f16;
typedef _Float16 hv2 __attribute__((ext_vector_type(2)));
typedef _Float16 f16x4 __attribute__((ext_vector_type(4)));
typedef _Float16 f16x8 __attribute__((ext_vector_type(8)));
typedef float f32x4 __attribute__((ext_vector_type(4)));

// ---------- misc0: transpose W_gcn (f16), transpose W1 (f16)
__global__ __launch_bounds__(WG) void k_misc0(const float* __restrict__ Wg,
                                              f16* __restrict__ Wgt,
                                              const float* __restrict__ W1,
                                              f16* __restrict__ W1t) {
    int b = blockIdx.x;
    if (b < 64) {  // Wgt[n*128+k] = Wg[k*128+n]
        int i = b * WG + threadIdx.x;
        int k = i & 127, nI = i >> 7;
        Wgt[i] = (f16)Wg[(size_t)k * 128 + nI];
    } else {  // W1t[n*256+k] = W1[k*128+n]
        int i = (b - 64) * WG + threadIdx.x;
        int k = i & 255, nI = i >> 8;
        W1t[i] = (f16)W1[(size_t)k * 128 + nI];
    }
}

// ============ fused A: mm_hpk (LDS-FREE GEMM) || edge histogram || cvt+bucket hist
// slot = b&3: 0 -> GEMM, 1/3 -> histogram (2 slots), 2 -> cvt + a-bucket histogram.
// LDS-free GEMM: B fragments direct from L1/L2-hot Wt; A fragments direct from x
// (lanes m,m+16,m+32,m+48 cover 128 contiguous bytes -> full-line coalescing).
// Kernel static LDS = 32 B -> histogram blocks run at full occupancy.
__global__ __launch_bounds__(WG) void k_fusedA(const float* __restrict__ A,
                                               const f16* __restrict__ Wt,
                                               __half2* __restrict__ Out, int n,
                                               const int* __restrict__ dst,
                                               int* __restrict__ deg,
                                               int* __restrict__ rank, int e,
                                               const int* __restrict__ pairs,
                                               float* __restrict__ outp, int n4,
                                               int* __restrict__ pcount,
                                               int* __restrict__ pboff, int slice,
                                               int nmm, int necnt, int ncvt) {
    __shared__ int hist[8];
    int b = blockIdx.x, slot = b & 3, idx = b >> 2;
    int tid = threadIdx.x;
    if (slot == 1 || slot == 3) {  // edge histogram: atomic-fabric bound
        int hid = idx * 2 + (slot >> 1);
        if (hid >= necnt) return;
        int i = hid * WG + tid;
        if (i < e) rank[i] = atomicAdd(&deg[dst[i]], 1);
        return;
    }
    if (slot == 2) {  // pair int->float cvt + per-block a-bucket histogram
        if (idx >= ncvt) return;
        if (tid < 8) hist[tid] = 0;
        __syncthreads();
        int i = idx * WG + tid;
        if (i < n4) {
            int4 v = ((const int4*)pairs)[i];
            ((float4*)outp)[i] = make_float4((float)v.x, (float)v.y, (float)v.z, (float)v.w);
            atomicAdd(&hist[v.x / slice], 1);
            atomicAdd(&hist[v.z / slice], 1);
        }
        __syncthreads();
        if (tid < 8) pboff[idx * 8 + tid] = atomicAdd(&pcount[tid], hist[tid]);
        return;
    }
    // slot 0: Hpk'[r][c] = half2 of (A@W)[r][{c,c+64}]   (raw, dinv folded into gather)
    if (idx >= nmm) return;
    const int row0 = idx * 64;
    const int wv = tid >> 6, lane = tid & 63, m = lane & 15, quad = lane >> 4;
    const int arow = row0 + wv * 16 + m;
    f16x8 af[4];
    if (arow < n) {
#pragma unroll
        for (int kk = 0; kk < 4; ++kk) {
            const float* ap = A + (size_t)arow * 128 + kk * 32 + quad * 8;
            float4 v0 = *(const float4*)ap;
            float4 v1 = *(const float4*)(ap + 4);
            af[kk] = (f16x8){(f16)v0.x, (f16)v0.y, (f16)v0.z, (f16)v0.w,
                             (f16)v1.x, (f16)v1.y, (f16)v1.z, (f16)v1.w};
        }
    } else {
#pragma unroll
        for (int kk = 0; kk < 4; ++kk)
            af[kk] = (f16x8){(f16)0.f, (f16)0.f, (f16)0.f, (f16)0.f,
                             (f16)0.f, (f16)0.f, (f16)0.f, (f16)0.f};
    }
    f32x4 acc[8];
#pragma unroll
    for (int t = 0; t < 8; ++t) acc[t] = (f32x4){0.f, 0.f, 0.f, 0.f};
#pragma unroll
    for (int kk = 0; kk < 4; ++kk) {
#pragma unroll
        for (int t = 0; t < 8; ++t) {
            f16x8 bf = *(const f16x8*)(Wt + (size_t)(t * 16 + m) * 128 + kk * 32 + quad * 8);
            acc[t] = __builtin_amdgcn_mfma_f32_16x16x32_f16(af[kk], bf, acc[t], 0, 0, 0);
        }
    }
#pragma unroll
    for (int r = 0; r < 4; ++r) {
        int row = row0 + wv * 16 + quad * 4 + r;
        if (row < n) {
#pragma unroll
            for (int t = 0; t < 4; ++t)
                Out[(size_t)row * 64 + t * 16 + m] =
                    __floats2half2_rn(acc[t][r], acc[t + 4][r]);
        }
    }
}

// ============ scan1: block-local exclusive scan + dinv ============
__global__ __launch_bounds__(WG) void k_scan1(const int* __restrict__ deg,
                                              float* __restrict__ dinv,
                                              int* __restrict__ base,
                                              int* __restrict__ bsum, int n) {
    __shared__ int t[WG];
    int tid = threadIdx.x;
    int i = blockIdx.x * WG + tid;
    int v = (i < n) ? deg[i] : 0;
    if (i < n) dinv[i] = rsqrtf((float)(v + 1));
    t[tid] = v;
    __syncthreads();
    for (int o = 1; o < WG; o <<= 1) {
        int add = (tid >= o) ? t[tid - o] : 0;
        __syncthreads();
        t[tid] += add;
        __syncthreads();
    }
    if (i < n) base[i] = t[tid] - v;  // block-local exclusive
    if (tid == WG - 1) bsum[blockIdx.x] = t[WG - 1];
}

// fused scan2+scan3: each block scans bsum in LDS, adds its own prefix.
__global__ __launch_bounds__(WG) void k_scan23(int* __restrict__ base,
                                               const int* __restrict__ bsum,
                                               int n, int e, int nb) {
    __shared__ int t[WG];
    int tid = threadIdx.x;
    int v = (tid < nb) ? bsum[tid] : 0;
    t[tid] = v;
    __syncthreads();
    for (int o = 1; o < WG; o <<= 1) {
        int add = (tid >= o) ? t[tid - o] : 0;
        __syncthreads();
        t[tid] += add;
        __syncthreads();
    }
    int off = t[blockIdx.x] - ((blockIdx.x < nb) ? bsum[blockIdx.x] : 0);
    int i = blockIdx.x * WG + tid;
    if (i < n) {
        base[i] += off;
        if (i == n - 1) base[n] = e;
    }
}

// ---------------- fill: no atomics — slot precomputed by rank
__global__ __launch_bounds__(WG) void k_fill(const int* __restrict__ src,
                                             const int* __restrict__ dst,
                                             const int* __restrict__ base,
                                             const int* __restrict__ rank,
                                             int* __restrict__ esrc, int e) {
    int i = blockIdx.x * WG + threadIdx.x;
    if (i >= e) return;
    esrc[base[dst[i]] + rank[i]] = src[i];
}

// ------------- gather: out_h[d] = (h[d]*dinv[d] + sum_in h[s]*dinv[s]) * dinv[d] + b
// 8-deep row batching (R5, kept).
__global__ __launch_bounds__(WG) void k_gather(const __half2* __restrict__ Hpk,
                                               const float* __restrict__ dinv,
                                               const float* __restrict__ bg,
                                               const int* __restrict__ base,
                                               const int* __restrict__ esrc,
                                               float* __restrict__ outh, int n) {
    int tid = threadIdx.x;
    int node = blockIdx.x * 16 + (tid >> 4);
    int sub = tid & 15;
    if (node >= n) return;
    float dv = dinv[node];
    int4 hh = *(const int4*)(Hpk + (size_t)node * 64 + 4 * sub);
    const int* hp = (const int*)&hh;
    float accl[4], acch[4];
#pragma unroll
    for (int k = 0; k < 4; ++k) {
        hv2 h = __builtin_bit_cast(hv2, hp[k]);
        accl[k] = (float)h[0] * dv;
        acch[k] = (float)h[1] * dv;
    }
    const int j = base[node], jend = base[node + 1];
    for (int j0 = j; j0 < jend; j0 += 8) {
        int s[8];
#pragma unroll
        for (int t = 0; t < 8; ++t) {
            int jt = j0 + t;
            s[t] = esrc[jt < jend ? jt : jend - 1];  // clamped: dup addr -> L1 hit
        }
        float ds[8];
#pragma unroll
        for (int t = 0; t < 8; ++t) ds[t] = (j0 + t < jend) ? dinv[s[t]] : 0.f;
        int4 r[8];
#pragma unroll
        for (int t = 0; t < 8; ++t)
            r[t] = *(const int4*)(Hpk + (size_t)s[t] * 64 + 4 * sub);
#pragma unroll
        for (int t = 0; t < 8; ++t) {
            const int* pr = (const int*)&r[t];
#pragma unroll
            for (int k = 0; k < 4; ++k) {
                hv2 h = __builtin_bit_cast(hv2, pr[k]);
                accl[k] = fmaf((float)h[0], ds[t], accl[k]);
                acch[k] = fmaf((float)h[1], ds[t], acch[k]);
            }
        }
    }
    float4 blo = *(const float4*)(bg + 4 * sub);
    float4 bhi = *(const float4*)(bg + 4 * sub + 64);
    *(float4*)&outh[(size_t)node * 128 + 4 * sub] =
        make_float4(fmaf(accl[0], dv, blo.x), fmaf(accl[1], dv, blo.y),
                    fmaf(accl[2], dv, blo.z), fmaf(accl[3], dv, blo.w));
    *(float4*)&outh[(size_t)node * 128 + 64 + 4 * sub] =
        make_float4(fmaf(acch[0], dv, bhi.x), fmaf(acch[1], dv, bhi.y),
                    fmaf(acch[2], dv, bhi.z), fmaf(acch[3], dv, bhi.w));
}

// ============ fused E: mm_uv (LDS-FREE MFMA) || pair scatter into 8 a-buckets
// slot = b&1: 0 -> mm_uv, 1 -> scatter.
// plist2 entry: x = b | (a_local<<16)  [valid for N<=65536], y = orig pair idx.
__global__ __launch_bounds__(WG) void k_fusedE(const float* __restrict__ A,
                                               const f16* __restrict__ W1t,
                                               const float* __restrict__ b1,
                                               __half2* __restrict__ Up,
                                               __half2* __restrict__ Vp, int n, int nmm,
                                               const int* __restrict__ pairs,
                                               const int* __restrict__ pcount,
                                               const int* __restrict__ pboff,
                                               int2* __restrict__ plist2,
                                               int n4, int ncvt, int slice) {
    __shared__ int cnt8[8];
    int b = blockIdx.x, slot = b & 1, idx = b >> 1;
    const int tid = threadIdx.x;
    if (slot == 1) {  // scatter pairs into bucket-ordered plist2
        if (idx >= ncvt) return;
        if (tid < 8) cnt8[tid] = 0;
        __syncthreads();
        int i = idx * WG + tid;
        if (i < n4) {
            int gb[8];
            int run = 0;
#pragma unroll
            for (int k = 0; k < 8; ++k) { gb[k] = run; run += pcount[k]; }
            int4 v = ((const int4*)pairs)[i];
            int bk0 = v.x / slice;
            int r0 = atomicAdd(&cnt8[bk0], 1);
            int d0 = gb[bk0] + pboff[idx * 8 + bk0] + r0;
            plist2[d0] = make_int2(v.y | ((v.x - bk0 * slice) << 16), 2 * i);
            int bk1 = v.z / slice;
            int r1 = atomicAdd(&cnt8[bk1], 1);
            int d1 = gb[bk1] + pboff[idx * 8 + bk1] + r1;
            plist2[d1] = make_int2(v.w | ((v.z - bk1 * slice) << 16), 2 * i + 1);
        }
        return;
    }
    // slot 0: mm_uv — U = A@W1a + b1, V = A@W1b; packed (c, c+64); LDS-free.
    if (idx >= nmm) return;
    const int row0 = idx * 64;
    const int wv = tid >> 6, lane = tid & 63, m = lane & 15, quad = lane >> 4;
    const int arow = row0 + wv * 16 + m;
    f16x8 af[4];
    if (arow < n) {
#pragma unroll
        for (int kk = 0; kk < 4; ++kk) {
            const float* ap = A + (size_t)arow * 128 + kk * 32 + quad * 8;
            float4 v0 = *(const float4*)ap;
            float4 v1 = *(const float4*)(ap + 4);
            af[kk] = (f16x8){(f16)v0.x, (f16)v0.y, (f16)v0.z, (f16)v0.w,
                             (f16)v1.x, (f16)v1.y, (f16)v1.z, (f16)v1.w};
        }
    } else {
#pragma unroll
        for (int kk = 0; kk < 4; ++kk)
            af[kk] = (f16x8){(f16)0.f, (f16)0.f, (f16)0.f, (f16)0.f,
                             (f16)0.f, (f16)0.f, (f16)0.f, (f16)0.f};
    }
    f32x4 acc[8];
#pragma unroll
    for (int ph = 0; ph < 2; ++ph) {
#pragma unroll
        for (int t = 0; t < 8; ++t) acc[t] = (f32x4){0.f, 0.f, 0.f, 0.f};
#pragma unroll
        for (int kk = 0; kk < 4; ++kk) {
#pragma unroll
            for (int t = 0; t < 8; ++t) {
                f16x8 bf = *(const f16x8*)(W1t + (size_t)(t * 16 + m) * 256 +
                                           ph * 128 + kk * 32 + quad * 8);
                acc[t] = __builtin_amdgcn_mfma_f32_16x16x32_f16(af[kk], bf, acc[t], 0, 0, 0);
            }
        }
        __half2* Out = ph ? Vp : Up;
#pragma unroll
        for (int t = 0; t < 4; ++t) {
            float bl = 0.f, bh = 0.f;
            if (!ph) { bl = b1[t * 16 + m]; bh = b1[t * 16 + m + 64]; }
#pragma unroll
            for (int r = 0; r < 4; ++r) {
                int row = row0 + wv * 16 + quad * 4 + r;
                if (row < n)
                    Out[(size_t)row * 64 + t * 16 + m] =
                        __floats2half2_rn(acc[t][r] + bl, acc[t + 4][r] + bh);
            }
        }
    }
}

// --------- bucketed pair MLP: blockIdx%8 -> bucket (XCD affinity via round-robin
// dispatch). Each XCD's U-reads confined to a 1.6MB slice -> L2-resident.
__global__ __launch_bounds__(WG) void k_pairx(const __half2* __restrict__ U,
                                              const __half2* __restrict__ V,
                                              const float* __restrict__ W2,
                                              const float* __restrict__ b2,
                                              const int* __restrict__ pcount,
                                              const int2* __restrict__ plist2,
                                              float* __restrict__ out_logit,
                                              int slice) {
    const int bkt = blockIdx.x & 7, blkid = blockIdx.x >> 3, NB = gridDim.x >> 3;
    int gbase = 0, cnt;
    {
        int c[8];
#pragma unroll
        for (int k = 0; k < 8; ++k) c[k] = pcount[k];
#pragma unroll
        for (int k = 0; k < 8; ++k)
            if (k < bkt) gbase += c[k];
        cnt = c[bkt];
    }
    const int2* pl = plist2 + gbase;
    const int abase = bkt * slice;
    const int lane = threadIdx.x & 63, wv = threadIdx.x >> 6;
    const int g = lane >> 4, sub = lane & 15;

    float4 w2lo = ((const float4*)W2)[sub];
    float4 w2hi = ((const float4*)(W2 + 64))[sub];
    hv2 w2h[4];
    w2h[0] = hv2{(f16)w2lo.x, (f16)w2hi.x};
    w2h[1] = hv2{(f16)w2lo.y, (f16)w2hi.y};
    w2h[2] = hv2{(f16)w2lo.z, (f16)w2hi.z};
    w2h[3] = hv2{(f16)w2lo.w, (f16)w2hi.w};
    const float bb = b2[0];
    const hv2 z2 = hv2{(f16)0.f, (f16)0.f};

    for (int pos = blkid * 64 + wv * 16; pos < cnt; pos += NB * 64) {
        int q0 = pos + g;
        if (q0 >= cnt) continue;
        int q1 = (q0 + 4 < cnt) ? q0 + 4 : q0;
        int q2 = (q0 + 8 < cnt) ? q0 + 8 : q0;
        int q3 = (q0 + 12 < cnt) ? q0 + 12 : q0;
        int2 e0 = pl[q0], e1 = pl[q1], e2 = pl[q2], e3 = pl[q3];
        int a0 = abase + (e0.x >> 16), b0 = e0.x & 0xFFFF;
        int a1 = abase + (e1.x >> 16), b1i = e1.x & 0xFFFF;
        int a2 = abase + (e2.x >> 16), b2i = e2.x & 0xFFFF;
        int a3 = abase + (e3.x >> 16), b3i = e3.x & 0xFFFF;

        int4 u0 = *(const int4*)(U + (size_t)a0 * 64 + 4 * sub);
        int4 v0 = *(const int4*)(V + (size_t)b0 * 64 + 4 * sub);
        int4 u1 = *(const int4*)(U + (size_t)a1 * 64 + 4 * sub);
        int4 v1 = *(const int4*)(V + (size_t)b1i * 64 + 4 * sub);
        int4 u2 = *(const int4*)(U + (size_t)a2 * 64 + 4 * sub);
        int4 v2 = *(const int4*)(V + (size_t)b2i * 64 + 4 * sub);
        int4 u3 = *(const int4*)(U + (size_t)a3 * 64 + 4 * sub);
        int4 v3 = *(const int4*)(V + (size_t)b3i * 64 + 4 * sub);

        const int* ui0 = (const int*)&u0;
        const int* vi0 = (const int*)&v0;
        const int* ui1 = (const int*)&u1;
        const int* vi1 = (const int*)&v1;
        const int* ui2 = (const int*)&u2;
        const int* vi2 = (const int*)&v2;
        const int* ui3 = (const int*)&u3;
        const int* vi3 = (const int*)&v3;

        float p0 = 0.f, p1 = 0.f, p2 = 0.f, p3 = 0.f;
#pragma unroll
        for (int k = 0; k < 4; ++k) {
            hv2 s0 = __builtin_bit_cast(hv2, ui0[k]) + __builtin_bit_cast(hv2, vi0[k]);
            hv2 s1 = __builtin_bit_cast(hv2, ui1[k]) + __builtin_bit_cast(hv2, vi1[k]);
            hv2 s2 = __builtin_bit_cast(hv2, ui2[k]) + __builtin_bit_cast(hv2, vi2[k]);
            hv2 s3 = __builtin_bit_cast(hv2, ui3[k]) + __builtin_bit_cast(hv2, vi3[k]);
            p0 = __builtin_amdgcn_fdot2(__builtin_elementwise_max(s0, z2), w2h[k], p0, false);
            p1 = __builtin_amdgcn_fdot2(__builtin_elementwise_max(s1, z2), w2h[k], p1, false);
            p2 = __builtin_amdgcn_fdot2(__builtin_elementwise_max(s2, z2), w2h[k], p2, false);
            p3 = __builtin_amdgcn_fdot2(__builtin_elementwise_max(s3, z2), w2h[k], p3, false);
        }
#pragma unroll
        for (int m = 1; m < 16; m <<= 1) {
            p0 += __shfl_xor(p0, m, 64);
            p1 += __shfl_xor(p1, m, 64);
            p2 += __shfl_xor(p2, m, 64);
            p3 += __shfl_xor(p3, m, 64);
        }
        if (sub == 0) {
            out_logit[e0.y] = p0 + bb;
            if (q0 + 4 < cnt) out_logit[e1.y] = p1 + bb;
            if (q0 + 8 < cnt) out_logit[e2.y] = p2 + bb;
            if (q0 + 12 < cnt) out_logit[e3.y] = p3 + bb;
        }
    }
}

extern "C" void kernel_launch(void* const* d_in, const int* in_sizes, int n_in,
                              void* d_out, int out_size, void* d_ws, size_t ws_size,
                              hipStream_t stream) {
    const float* x     = (const float*)d_in[0];
    const int*   eidx  = (const int*)d_in[1];
    const int*   pairs = (const int*)d_in[2];
    const float* W_gcn = (const float*)d_in[3];
    const float* b_gcn = (const float*)d_in[4];
    const float* W1    = (const float*)d_in[5];
    const float* b1    = (const float*)d_in[6];
    const float* W2    = (const float*)d_in[7];
    const float* b2    = (const float*)d_in[8];

    const int N = in_sizes[0] / 128;
    const int E = in_sizes[1] / 2;
    const int P = in_sizes[2] / 2;
    const int* esrc_in = eidx;
    const int* edst_in = eidx + E;
    const int slice = (N + 7) / 8;  // a-bucket width (N<=65536 for plist2 packing)

    // workspace layout (4-byte units)
    float* ws      = (float*)d_ws;
    int*   deg     = (int*)d_ws;                  // [N]
    int*   pcount  = (int*)d_ws + N;              // [8] (contiguous: one memset)
    float* dinv    = ws + 65536;                  // [N]
    int*   base    = (int*)(ws + 131072);         // [N+1]
    int*   bsum    = (int*)(ws + 196608);         // [256]
    f16*   Wt_gcn  = (f16*)(ws + 197120);         // [128*128] f16
    f16*   W1t     = (f16*)(ws + 205312);         // [128*256] f16
    int*   pboff   = (int*)(ws + 221696);         // [ncvt*8] <= 16384
    int*   rank    = (int*)(ws + 238080);         // [E]
    int*   ecsr    = rank + (size_t)E;            // [E]
    __half2* Hpk   = (__half2*)(ecsr + (size_t)E);  // [N*64]  (raw h, packed c,c+64)
    __half2* Upk   = Hpk + (size_t)N * 64;        // [N*64]
    __half2* Vpk   = Upk + (size_t)N * 64;        // [N*64]
    // plist2 aliases Hpk: written by fusedE (after k_gather's last Hpk read),
    // read by k_pairx. P int2 = 8MB <= Hpk's 12.8MB.
    int2*  plist2  = (int2*)Hpk;

    float* out_logit = (float*)d_out;             // [P]
    float* out_pairs = out_logit + P;             // [2P] as float
    float* out_h     = out_logit + 3 * (size_t)P; // [N*128]

    const int nb    = (N + WG - 1) / WG;          // 196
    const int nmm   = (N + 63) / 64;              // 782
    const int necnt = (E + WG - 1) / WG;          // 3125
    const int ncvt  = (P / 2 + WG - 1) / WG;      // 1954
    int gmax = nmm;
    int h2 = (necnt + 1) / 2;
    if (h2 > gmax) gmax = h2;
    if (ncvt > gmax) gmax = ncvt;
    int emax = (nmm > ncvt) ? nmm : ncvt;
    dim3 blk(WG);

    hipMemsetAsync(deg, 0, (size_t)N * 4 + 32, stream);  // deg + pcount
    // transposes (Wgt consumed by fusedA, so must precede it)
    k_misc0  <<<192, blk, 0, stream>>>(W_gcn, Wt_gcn, W1, W1t);
    // A: mm_hpk (LDS-free) || edge histogram || pair cvt + bucket hist
    k_fusedA <<<4 * gmax, blk, 0, stream>>>(x, Wt_gcn, Hpk, N,
                                            edst_in, deg, rank, E,
                                            pairs, out_pairs, P / 2,
                                            pcount, pboff, slice,
                                            nmm, necnt, ncvt);
    k_scan1  <<<nb, blk, 0, stream>>>(deg, dinv, base, bsum, N);
    k_scan23 <<<nb, blk, 0, stream>>>(base, bsum, N, E, nb);
    k_fill   <<<necnt, blk, 0, stream>>>(esrc_in, edst_in, base, rank, ecsr, E);
    k_gather <<<(N + 15) / 16, blk, 0, stream>>>(Hpk, dinv, b_gcn, base, ecsr, out_h, N);
    // E: mm_uv (LDS-free) || pair scatter (plist2 build overlaps MFMA)
    k_fusedE <<<2 * emax, blk, 0, stream>>>(out_h, W1t, b1, Upk, Vpk, N, nmm,
                                            pairs, pcount, pboff, plist2,
                                            P / 2, ncvt, slice);
    // bucketed pair MLP: bid%8 -> bucket -> XCD
    k_pairx  <<<4096, blk, 0, stream>>>(Upk, Vpk, W2, b2, pcount, plist2,
                                        out_logit, slice);
}

// Round 8
// 260.393 us; speedup vs baseline: 1.2551x; 1.2551x over previous
//
#include <hip/hip_runtime.h>
#include <hip/hip_fp16.h>

#define WG 256

typedef _Float16 f16;
typedef _Float16 hv2 __attribute__((ext_vector_type(2)));
typedef _Float16 f16x4 __attribute__((ext_vector_type(4)));
typedef _Float16 f16x8 __attribute__((ext_vector_type(8)));
typedef float f32x4 __attribute__((ext_vector_type(4)));

// ---------- misc0: transpose W_gcn (f16), transpose W1 (f16)
__global__ __launch_bounds__(WG) void k_misc0(const float* __restrict__ Wg,
                                              f16* __restrict__ Wgt,
                                              const float* __restrict__ W1,
                                              f16* __restrict__ W1t) {
    int b = blockIdx.x;
    if (b < 64) {  // Wgt[n*128+k] = Wg[k*128+n]
        int i = b * WG + threadIdx.x;
        int k = i & 127, nI = i >> 7;
        Wgt[i] = (f16)Wg[(size_t)k * 128 + nI];
    } else {  // W1t[n*256+k] = W1[k*128+n]
        int i = (b - 64) * WG + threadIdx.x;
        int k = i & 255, nI = i >> 8;
        W1t[i] = (f16)W1[(size_t)k * 128 + nI];
    }
}

// ============ fused A: mm_hpk (A direct, B in 17KB LDS halves) || edge hist || cvt
// slot = b&3: 0 -> GEMM, 1/3 -> histogram (2 slots), 2 -> cvt + a-bucket histogram.
// LDS = 17.4KB -> 8 blocks/CU (wave-limited), so atomic slots keep full concurrency,
// while MFMA operands still come from LDS (no per-MFMA global-latency chain, cf R7).
__global__ __launch_bounds__(WG) void k_fusedA(const float* __restrict__ A,
                                               const f16* __restrict__ Wt,
                                               __half2* __restrict__ Out, int n,
                                               const int* __restrict__ dst,
                                               int* __restrict__ deg,
                                               int* __restrict__ rank, int e,
                                               const int* __restrict__ pairs,
                                               float* __restrict__ outp, int n4,
                                               int* __restrict__ pcount,
                                               int* __restrict__ pboff, int slice,
                                               int nmm, int necnt, int ncvt) {
    __shared__ __align__(16) char smem[64 * 136 * 2];
    int b = blockIdx.x, slot = b & 3, idx = b >> 2;
    int tid = threadIdx.x;
    if (slot == 1 || slot == 3) {  // edge histogram: atomic-fabric bound
        int hid = idx * 2 + (slot >> 1);
        if (hid >= necnt) return;
        int i = hid * WG + tid;
        if (i < e) rank[i] = atomicAdd(&deg[dst[i]], 1);
        return;
    }
    if (slot == 2) {  // pair int->float cvt + per-block a-bucket histogram
        if (idx >= ncvt) return;
        int* hist = (int*)smem;
        if (tid < 8) hist[tid] = 0;
        __syncthreads();
        int i = idx * WG + tid;
        if (i < n4) {
            int4 v = ((const int4*)pairs)[i];
            ((float4*)outp)[i] = make_float4((float)v.x, (float)v.y, (float)v.z, (float)v.w);
            atomicAdd(&hist[v.x / slice], 1);
            atomicAdd(&hist[v.z / slice], 1);
        }
        __syncthreads();
        if (tid < 8) pboff[idx * 8 + tid] = atomicAdd(&pcount[tid], hist[tid]);
        return;
    }
    // slot 0: Hpk'[r][c] = half2 of (A@W)[r][{c,c+64}]   (raw, dinv folded in gather)
    if (idx >= nmm) return;
    f16(*Bs)[136] = (f16(*)[136])smem;
    const int row0 = idx * 64;
    const int wv = tid >> 6, lane = tid & 63, m = lane & 15, quad = lane >> 4;
    const int arow = row0 + wv * 16 + m;
    f16x8 af[4];
    if (arow < n) {
#pragma unroll
        for (int kk = 0; kk < 4; ++kk) {
            const float* ap = A + (size_t)arow * 128 + kk * 32 + quad * 8;
            float4 v0 = *(const float4*)ap;
            float4 v1 = *(const float4*)(ap + 4);
            af[kk] = (f16x8){(f16)v0.x, (f16)v0.y, (f16)v0.z, (f16)v0.w,
                             (f16)v1.x, (f16)v1.y, (f16)v1.z, (f16)v1.w};
        }
    } else {
#pragma unroll
        for (int kk = 0; kk < 4; ++kk)
            af[kk] = (f16x8){(f16)0.f, (f16)0.f, (f16)0.f, (f16)0.f,
                             (f16)0.f, (f16)0.f, (f16)0.f, (f16)0.f};
    }
    f32x4 acc[8];
#pragma unroll
    for (int t = 0; t < 8; ++t) acc[t] = (f32x4){0.f, 0.f, 0.f, 0.f};
#pragma unroll
    for (int half = 0; half < 2; ++half) {
        for (int f = tid; f < 64 * 16; f += WG) {
            int r = f >> 4, c = f & 15;
            *(float4*)&Bs[r][c * 8] = ((const float4*)Wt)[(half * 64 + r) * 16 + c];
        }
        __syncthreads();
#pragma unroll
        for (int kk = 0; kk < 4; ++kk) {
#pragma unroll
            for (int t = 0; t < 4; ++t) {
                f16x8 bf = *(f16x8*)&Bs[t * 16 + m][kk * 32 + quad * 8];
                acc[half * 4 + t] =
                    __builtin_amdgcn_mfma_f32_16x16x32_f16(af[kk], bf, acc[half * 4 + t], 0, 0, 0);
            }
        }
        __syncthreads();
    }
#pragma unroll
    for (int r = 0; r < 4; ++r) {
        int row = row0 + wv * 16 + quad * 4 + r;
        if (row < n) {
#pragma unroll
            for (int t = 0; t < 4; ++t)
                Out[(size_t)row * 64 + t * 16 + m] =
                    __floats2half2_rn(acc[t][r], acc[t + 4][r]);
        }
    }
}

// ============ scan1: block-local exclusive scan + dinv ============
__global__ __launch_bounds__(WG) void k_scan1(const int* __restrict__ deg,
                                              float* __restrict__ dinv,
                                              int* __restrict__ base,
                                              int* __restrict__ bsum, int n) {
    __shared__ int t[WG];
    int tid = threadIdx.x;
    int i = blockIdx.x * WG + tid;
    int v = (i < n) ? deg[i] : 0;
    if (i < n) dinv[i] = rsqrtf((float)(v + 1));
    t[tid] = v;
    __syncthreads();
    for (int o = 1; o < WG; o <<= 1) {
        int add = (tid >= o) ? t[tid - o] : 0;
        __syncthreads();
        t[tid] += add;
        __syncthreads();
    }
    if (i < n) base[i] = t[tid] - v;  // block-local exclusive
    if (tid == WG - 1) bsum[blockIdx.x] = t[WG - 1];
}

// fused scan2+scan3: each block scans bsum in LDS, adds its own prefix.
__global__ __launch_bounds__(WG) void k_scan23(int* __restrict__ base,
                                               const int* __restrict__ bsum,
                                               int n, int e, int nb) {
    __shared__ int t[WG];
    int tid = threadIdx.x;
    int v = (tid < nb) ? bsum[tid] : 0;
    t[tid] = v;
    __syncthreads();
    for (int o = 1; o < WG; o <<= 1) {
        int add = (tid >= o) ? t[tid - o] : 0;
        __syncthreads();
        t[tid] += add;
        __syncthreads();
    }
    int off = t[blockIdx.x] - ((blockIdx.x < nb) ? bsum[blockIdx.x] : 0);
    int i = blockIdx.x * WG + tid;
    if (i < n) {
        base[i] += off;
        if (i == n - 1) base[n] = e;
    }
}

// ---------------- fill: no atomics — slot precomputed by rank
__global__ __launch_bounds__(WG) void k_fill(const int* __restrict__ src,
                                             const int* __restrict__ dst,
                                             const int* __restrict__ base,
                                             const int* __restrict__ rank,
                                             int* __restrict__ esrc, int e) {
    int i = blockIdx.x * WG + threadIdx.x;
    if (i >= e) return;
    esrc[base[dst[i]] + rank[i]] = src[i];
}

// ------------- gather: out_h[d] = (h[d]*dinv[d] + sum_in h[s]*dinv[s]) * dinv[d] + b
// 8-deep row batching (R5, kept).
__global__ __launch_bounds__(WG) void k_gather(const __half2* __restrict__ Hpk,
                                               const float* __restrict__ dinv,
                                               const float* __restrict__ bg,
                                               const int* __restrict__ base,
                                               const int* __restrict__ esrc,
                                               float* __restrict__ outh, int n) {
    int tid = threadIdx.x;
    int node = blockIdx.x * 16 + (tid >> 4);
    int sub = tid & 15;
    if (node >= n) return;
    float dv = dinv[node];
    int4 hh = *(const int4*)(Hpk + (size_t)node * 64 + 4 * sub);
    const int* hp = (const int*)&hh;
    float accl[4], acch[4];
#pragma unroll
    for (int k = 0; k < 4; ++k) {
        hv2 h = __builtin_bit_cast(hv2, hp[k]);
        accl[k] = (float)h[0] * dv;
        acch[k] = (float)h[1] * dv;
    }
    const int j = base[node], jend = base[node + 1];
    for (int j0 = j; j0 < jend; j0 += 8) {
        int s[8];
#pragma unroll
        for (int t = 0; t < 8; ++t) {
            int jt = j0 + t;
            s[t] = esrc[jt < jend ? jt : jend - 1];  // clamped: dup addr -> L1 hit
        }
        float ds[8];
#pragma unroll
        for (int t = 0; t < 8; ++t) ds[t] = (j0 + t < jend) ? dinv[s[t]] : 0.f;
        int4 r[8];
#pragma unroll
        for (int t = 0; t < 8; ++t)
            r[t] = *(const int4*)(Hpk + (size_t)s[t] * 64 + 4 * sub);
#pragma unroll
        for (int t = 0; t < 8; ++t) {
            const int* pr = (const int*)&r[t];
#pragma unroll
            for (int k = 0; k < 4; ++k) {
                hv2 h = __builtin_bit_cast(hv2, pr[k]);
                accl[k] = fmaf((float)h[0], ds[t], accl[k]);
                acch[k] = fmaf((float)h[1], ds[t], acch[k]);
            }
        }
    }
    float4 blo = *(const float4*)(bg + 4 * sub);
    float4 bhi = *(const float4*)(bg + 4 * sub + 64);
    *(float4*)&outh[(size_t)node * 128 + 4 * sub] =
        make_float4(fmaf(accl[0], dv, blo.x), fmaf(accl[1], dv, blo.y),
                    fmaf(accl[2], dv, blo.z), fmaf(accl[3], dv, blo.w));
    *(float4*)&outh[(size_t)node * 128 + 64 + 4 * sub] =
        make_float4(fmaf(acch[0], dv, bhi.x), fmaf(acch[1], dv, bhi.y),
                    fmaf(acch[2], dv, bhi.z), fmaf(acch[3], dv, bhi.w));
}

// ============ fused E: mm_uv (A direct, B in 17KB LDS halves) || pair scatter
// slot = b&1: 0 -> mm_uv, 1 -> scatter.
// plist2 entry: x = b | (a_local<<16)  [valid for N<=65536], y = orig pair idx.
__global__ __launch_bounds__(WG) void k_fusedE(const float* __restrict__ A,
                                               const f16* __restrict__ W1t,
                                               const float* __restrict__ b1,
                                               __half2* __restrict__ Up,
                                               __half2* __restrict__ Vp, int n, int nmm,
                                               const int* __restrict__ pairs,
                                               const int* __restrict__ pcount,
                                               const int* __restrict__ pboff,
                                               int2* __restrict__ plist2,
                                               int n4, int ncvt, int slice) {
    __shared__ __align__(16) char smem[64 * 136 * 2];
    int b = blockIdx.x, slot = b & 1, idx = b >> 1;
    const int tid = threadIdx.x;
    if (slot == 1) {  // scatter pairs into bucket-ordered plist2
        if (idx >= ncvt) return;
        int* cnt8 = (int*)smem;
        if (tid < 8) cnt8[tid] = 0;
        __syncthreads();
        int i = idx * WG + tid;
        if (i < n4) {
            int gb[8];
            int run = 0;
#pragma unroll
            for (int k = 0; k < 8; ++k) { gb[k] = run; run += pcount[k]; }
            int4 v = ((const int4*)pairs)[i];
            int bk0 = v.x / slice;
            int r0 = atomicAdd(&cnt8[bk0], 1);
            int d0 = gb[bk0] + pboff[idx * 8 + bk0] + r0;
            plist2[d0] = make_int2(v.y | ((v.x - bk0 * slice) << 16), 2 * i);
            int bk1 = v.z / slice;
            int r1 = atomicAdd(&cnt8[bk1], 1);
            int d1 = gb[bk1] + pboff[idx * 8 + bk1] + r1;
            plist2[d1] = make_int2(v.w | ((v.z - bk1 * slice) << 16), 2 * i + 1);
        }
        return;
    }
    // slot 0: mm_uv — U = A@W1a + b1, V = A@W1b; packed (c, c+64)
    if (idx >= nmm) return;
    f16(*Bs)[136] = (f16(*)[136])smem;
    const int row0 = idx * 64;
    const int wv = tid >> 6, lane = tid & 63, m = lane & 15, quad = lane >> 4;
    const int arow = row0 + wv * 16 + m;
    f16x8 af[4];
    if (arow < n) {
#pragma unroll
        for (int kk = 0; kk < 4; ++kk) {
            const float* ap = A + (size_t)arow * 128 + kk * 32 + quad * 8;
            float4 v0 = *(const float4*)ap;
            float4 v1 = *(const float4*)(ap + 4);
            af[kk] = (f16x8){(f16)v0.x, (f16)v0.y, (f16)v0.z, (f16)v0.w,
                             (f16)v1.x, (f16)v1.y, (f16)v1.z, (f16)v1.w};
        }
    } else {
#pragma unroll
        for (int kk = 0; kk < 4; ++kk)
            af[kk] = (f16x8){(f16)0.f, (f16)0.f, (f16)0.f, (f16)0.f,
                             (f16)0.f, (f16)0.f, (f16)0.f, (f16)0.f};
    }
    f32x4 acc[8];
#pragma unroll
    for (int ph = 0; ph < 2; ++ph) {
#pragma unroll
        for (int t = 0; t < 8; ++t) acc[t] = (f32x4){0.f, 0.f, 0.f, 0.f};
#pragma unroll
        for (int half = 0; half < 2; ++half) {
            for (int f = tid; f < 64 * 16; f += WG) {
                int r = f >> 4, c = f & 15;
                *(float4*)&Bs[r][c * 8] =
                    *(const float4*)(W1t + (size_t)(half * 64 + r) * 256 + ph * 128 + c * 8);
            }
            __syncthreads();
#pragma unroll
            for (int kk = 0; kk < 4; ++kk) {
#pragma unroll
                for (int t = 0; t < 4; ++t) {
                    f16x8 bf = *(f16x8*)&Bs[t * 16 + m][kk * 32 + quad * 8];
                    acc[half * 4 + t] =
                        __builtin_amdgcn_mfma_f32_16x16x32_f16(af[kk], bf, acc[half * 4 + t], 0, 0, 0);
                }
            }
            __syncthreads();
        }
        __half2* Out = ph ? Vp : Up;
#pragma unroll
        for (int t = 0; t < 4; ++t) {
            float bl = 0.f, bh = 0.f;
            if (!ph) { bl = b1[t * 16 + m]; bh = b1[t * 16 + m + 64]; }
#pragma unroll
            for (int r = 0; r < 4; ++r) {
                int row = row0 + wv * 16 + quad * 4 + r;
                if (row < n)
                    Out[(size_t)row * 64 + t * 16 + m] =
                        __floats2half2_rn(acc[t][r] + bl, acc[t + 4][r] + bh);
            }
        }
    }
}

// --------- bucketed pair MLP: blockIdx%8 -> bucket (XCD affinity via round-robin
// dispatch). Each XCD's U-reads confined to a 1.6MB slice -> L2-resident.
__global__ __launch_bounds__(WG) void k_pairx(const __half2* __restrict__ U,
                                              const __half2* __restrict__ V,
                                              const float* __restrict__ W2,
                                              const float* __restrict__ b2,
                                              const int* __restrict__ pcount,
                                              const int2* __restrict__ plist2,
                                              float* __restrict__ out_logit,
                                              int slice) {
    const int bkt = blockIdx.x & 7, blkid = blockIdx.x >> 3, NB = gridDim.x >> 3;
    int gbase = 0, cnt;
    {
        int c[8];
#pragma unroll
        for (int k = 0; k < 8; ++k) c[k] = pcount[k];
#pragma unroll
        for (int k = 0; k < 8; ++k)
            if (k < bkt) gbase += c[k];
        cnt = c[bkt];
    }
    const int2* pl = plist2 + gbase;
    const int abase = bkt * slice;
    const int lane = threadIdx.x & 63, wv = threadIdx.x >> 6;
    const int g = lane >> 4, sub = lane & 15;

    float4 w2lo = ((const float4*)W2)[sub];
    float4 w2hi = ((const float4*)(W2 + 64))[sub];
    hv2 w2h[4];
    w2h[0] = hv2{(f16)w2lo.x, (f16)w2hi.x};
    w2h[1] = hv2{(f16)w2lo.y, (f16)w2hi.y};
    w2h[2] = hv2{(f16)w2lo.z, (f16)w2hi.z};
    w2h[3] = hv2{(f16)w2lo.w, (f16)w2hi.w};
    const float bb = b2[0];
    const hv2 z2 = hv2{(f16)0.f, (f16)0.f};

    for (int pos = blkid * 64 + wv * 16; pos < cnt; pos += NB * 64) {
        int q0 = pos + g;
        if (q0 >= cnt) continue;
        int q1 = (q0 + 4 < cnt) ? q0 + 4 : q0;
        int q2 = (q0 + 8 < cnt) ? q0 + 8 : q0;
        int q3 = (q0 + 12 < cnt) ? q0 + 12 : q0;
        int2 e0 = pl[q0], e1 = pl[q1], e2 = pl[q2], e3 = pl[q3];
        int a0 = abase + (e0.x >> 16), b0 = e0.x & 0xFFFF;
        int a1 = abase + (e1.x >> 16), b1i = e1.x & 0xFFFF;
        int a2 = abase + (e2.x >> 16), b2i = e2.x & 0xFFFF;
        int a3 = abase + (e3.x >> 16), b3i = e3.x & 0xFFFF;

        int4 u0 = *(const int4*)(U + (size_t)a0 * 64 + 4 * sub);
        int4 v0 = *(const int4*)(V + (size_t)b0 * 64 + 4 * sub);
        int4 u1 = *(const int4*)(U + (size_t)a1 * 64 + 4 * sub);
        int4 v1 = *(const int4*)(V + (size_t)b1i * 64 + 4 * sub);
        int4 u2 = *(const int4*)(U + (size_t)a2 * 64 + 4 * sub);
        int4 v2 = *(const int4*)(V + (size_t)b2i * 64 + 4 * sub);
        int4 u3 = *(const int4*)(U + (size_t)a3 * 64 + 4 * sub);
        int4 v3 = *(const int4*)(V + (size_t)b3i * 64 + 4 * sub);

        const int* ui0 = (const int*)&u0;
        const int* vi0 = (const int*)&v0;
        const int* ui1 = (const int*)&u1;
        const int* vi1 = (const int*)&v1;
        const int* ui2 = (const int*)&u2;
        const int* vi2 = (const int*)&v2;
        const int* ui3 = (const int*)&u3;
        const int* vi3 = (const int*)&v3;

        float p0 = 0.f, p1 = 0.f, p2 = 0.f, p3 = 0.f;
#pragma unroll
        for (int k = 0; k < 4; ++k) {
            hv2 s0 = __builtin_bit_cast(hv2, ui0[k]) + __builtin_bit_cast(hv2, vi0[k]);
            hv2 s1 = __builtin_bit_cast(hv2, ui1[k]) + __builtin_bit_cast(hv2, vi1[k]);
            hv2 s2 = __builtin_bit_cast(hv2, ui2[k]) + __builtin_bit_cast(hv2, vi2[k]);
            hv2 s3 = __builtin_bit_cast(hv2, ui3[k]) + __builtin_bit_cast(hv2, vi3[k]);
            p0 = __builtin_amdgcn_fdot2(__builtin_elementwise_max(s0, z2), w2h[k], p0, false);
            p1 = __builtin_amdgcn_fdot2(__builtin_elementwise_max(s1, z2), w2h[k], p1, false);
            p2 = __builtin_amdgcn_fdot2(__builtin_elementwise_max(s2, z2), w2h[k], p2, false);
            p3 = __builtin_amdgcn_fdot2(__builtin_elementwise_max(s3, z2), w2h[k], p3, false);
        }
#pragma unroll
        for (int m = 1; m < 16; m <<= 1) {
            p0 += __shfl_xor(p0, m, 64);
            p1 += __shfl_xor(p1, m, 64);
            p2 += __shfl_xor(p2, m, 64);
            p3 += __shfl_xor(p3, m, 64);
        }
        if (sub == 0) {
            out_logit[e0.y] = p0 + bb;
            if (q0 + 4 < cnt) out_logit[e1.y] = p1 + bb;
            if (q0 + 8 < cnt) out_logit[e2.y] = p2 + bb;
            if (q0 + 12 < cnt) out_logit[e3.y] = p3 + bb;
        }
    }
}

extern "C" void kernel_launch(void* const* d_in, const int* in_sizes, int n_in,
                              void* d_out, int out_size, void* d_ws, size_t ws_size,
                              hipStream_t stream) {
    const float* x     = (const float*)d_in[0];
    const int*   eidx  = (const int*)d_in[1];
    const int*   pairs = (const int*)d_in[2];
    const float* W_gcn = (const float*)d_in[3];
    const float* b_gcn = (const float*)d_in[4];
    const float* W1    = (const float*)d_in[5];
    const float* b1    = (const float*)d_in[6];
    const float* W2    = (const float*)d_in[7];
    const float* b2    = (const float*)d_in[8];

    const int N = in_sizes[0] / 128;
    const int E = in_sizes[1] / 2;
    const int P = in_sizes[2] / 2;
    const int* esrc_in = eidx;
    const int* edst_in = eidx + E;
    const int slice = (N + 7) / 8;  // a-bucket width (N<=65536 for plist2 packing)

    // workspace layout (4-byte units)
    float* ws      = (float*)d_ws;
    int*   deg     = (int*)d_ws;                  // [N]
    int*   pcount  = (int*)d_ws + N;              // [8] (contiguous: one memset)
    float* dinv    = ws + 65536;                  // [N]
    int*   base    = (int*)(ws + 131072);         // [N+1]
    int*   bsum    = (int*)(ws + 196608);         // [256]
    f16*   Wt_gcn  = (f16*)(ws + 197120);         // [128*128] f16
    f16*   W1t     = (f16*)(ws + 205312);         // [128*256] f16
    int*   pboff   = (int*)(ws + 221696);         // [ncvt*8] <= 16384
    int*   rank    = (int*)(ws + 238080);         // [E]
    int*   ecsr    = rank + (size_t)E;            // [E]
    __half2* Hpk   = (__half2*)(ecsr + (size_t)E);  // [N*64]  (raw h, packed c,c+64)
    __half2* Upk   = Hpk + (size_t)N * 64;        // [N*64]
    __half2* Vpk   = Upk + (size_t)N * 64;        // [N*64]
    // plist2 aliases Hpk: written by fusedE (after k_gather's last Hpk read),
    // read by k_pairx. P int2 = 8MB <= Hpk's 12.8MB.
    int2*  plist2  = (int2*)Hpk;

    float* out_logit = (float*)d_out;             // [P]
    float* out_pairs = out_logit + P;             // [2P] as float
    float* out_h     = out_logit + 3 * (size_t)P; // [N*128]

    const int nb    = (N + WG - 1) / WG;          // 196
    const int nmm   = (N + 63) / 64;              // 782
    const int necnt = (E + WG - 1) / WG;          // 3125
    const int ncvt  = (P / 2 + WG - 1) / WG;      // 1954
    int gmax = nmm;
    int h2 = (necnt + 1) / 2;
    if (h2 > gmax) gmax = h2;
    if (ncvt > gmax) gmax = ncvt;
    int emax = (nmm > ncvt) ? nmm : ncvt;
    dim3 blk(WG);

    hipMemsetAsync(deg, 0, (size_t)N * 4 + 32, stream);  // deg + pcount
    // transposes (Wgt consumed by fusedA, so must precede it)
    k_misc0  <<<192, blk, 0, stream>>>(W_gcn, Wt_gcn, W1, W1t);
    // A: mm_hpk (17KB-LDS GEMM) || edge histogram || pair cvt + bucket hist
    k_fusedA <<<4 * gmax, blk, 0, stream>>>(x, Wt_gcn, Hpk, N,
                                            edst_in, deg, rank, E,
                                            pairs, out_pairs, P / 2,
                                            pcount, pboff, slice,
                                            nmm, necnt, ncvt);
    k_scan1  <<<nb, blk, 0, stream>>>(deg, dinv, base, bsum, N);
    k_scan23 <<<nb, blk, 0, stream>>>(base, bsum, N, E, nb);
    k_fill   <<<necnt, blk, 0, stream>>>(esrc_in, edst_in, base, rank, ecsr, E);
    k_gather <<<(N + 15) / 16, blk, 0, stream>>>(Hpk, dinv, b_gcn, base, ecsr, out_h, N);
    // E: mm_uv (17KB-LDS) || pair scatter (plist2 build overlaps MFMA)
    k_fusedE <<<2 * emax, blk, 0, stream>>>(out_h, W1t, b1, Upk, Vpk, N, nmm,
                                            pairs, pcount, pboff, plist2,
                                            P / 2, ncvt, slice);
    // bucketed pair MLP: bid%8 -> bucket -> XCD
    k_pairx  <<<4096, blk, 0, stream>>>(Upk, Vpk, W2, b2, pcount, plist2,
                                        out_logit, slice);
}